// Round 2
// baseline (276.375 us; speedup 1.0000x reference)
//
#include <hip/hip_runtime.h>
#include <stdint.h>

typedef unsigned short u16;
typedef __attribute__((ext_vector_type(8))) __bf16 bvec8;
typedef __attribute__((ext_vector_type(4))) float f32x4;

__device__ __forceinline__ u16 f32_to_bf16(float f) {
    uint32_t u = __float_as_uint(f);
    u += 0x7fffu + ((u >> 16) & 1u);   // round-to-nearest-even
    return (u16)(u >> 16);
}

// async global->LDS, 16B per lane; LDS dest = wave-uniform base + lane*16
__device__ __forceinline__ void gl2lds16(const u16* g, u16* l) {
    void* gnc = const_cast<void*>((const void*)g);
    __builtin_amdgcn_global_load_lds(
        (__attribute__((address_space(1))) uint32_t*)gnc,
        (__attribute__((address_space(3))) uint32_t*)((void*)l),
        16, 0, 0);
}

// fp32 -> bf16 (RNE), vectorized: one thread converts 4 elements
__global__ __launch_bounds__(256) void cvt_f32_bf16(const float* __restrict__ in,
                                                    u16* __restrict__ out, int n4) {
    int i = blockIdx.x * 256 + threadIdx.x;
    if (i < n4) {
        float4 v = ((const float4*)in)[i];
        ushort4 o;
        o.x = f32_to_bf16(v.x); o.y = f32_to_bf16(v.y);
        o.z = f32_to_bf16(v.z); o.w = f32_to_bf16(v.w);
        ((ushort4*)out)[i] = o;
    }
}

// ---------------------------------------------------------------------------
// GEMM (B^T layout): C[M][N] = A[M][K] * B[N][K]^T + bias[N]
// A,B bf16; bias fp32; fp32 accum; output bf16 or fp32 (template).
// 128x128 tile, BK=32, 256 threads (4 waves as 2x2 of 64x64)
// ---------------------------------------------------------------------------
#define BM 128
#define BN 128
#define BK 32

template <bool OUT_BF16>
__global__ __launch_bounds__(256) void gemm_bt_bias(
    const u16* __restrict__ A, const u16* __restrict__ B,
    const float* __restrict__ bias, void* __restrict__ Cv,
    int M, int N, int K)
{
    __shared__ __attribute__((aligned(16))) u16 As[BM * BK];
    __shared__ __attribute__((aligned(16))) u16 Bs[BN * BK];

    const int tid  = threadIdx.x;
    const int wave = tid >> 6;
    const int lane = tid & 63;
    const int col  = lane & 15;
    const int quad = lane >> 4;

    const int m0 = blockIdx.y * BM;
    const int n0 = blockIdx.x * BN;
    const int wm = (wave >> 1) * 64;
    const int wn = (wave & 1) * 64;

    const int srow   = lane >> 2;   // 0..15 within a 16-row group
    const int schunk = lane & 3;    // which 16B chunk of the 64B row
    const u16* Ag = A + (size_t)(m0 + wave * 32) * K;
    const u16* Bg = B + (size_t)(n0 + wave * 32) * K;

    f32x4 acc[4][4];
#pragma unroll
    for (int i = 0; i < 4; i++)
#pragma unroll
        for (int j = 0; j < 4; j++) acc[i][j] = f32x4{0.f, 0.f, 0.f, 0.f};

    for (int k0 = 0; k0 < K; k0 += BK) {
        __syncthreads();
#pragma unroll
        for (int g = 0; g < 2; ++g) {
            gl2lds16(Ag + (size_t)(g * 16 + srow) * K + k0 + schunk * 8, &As[(wave * 2 + g) * 512]);
            gl2lds16(Bg + (size_t)(g * 16 + srow) * K + k0 + schunk * 8, &Bs[(wave * 2 + g) * 512]);
        }
        __syncthreads();   // drains vmcnt(0) -> tiles visible

        bvec8 af[4], bfv[4];
#pragma unroll
        for (int mt = 0; mt < 4; mt++) af[mt]  = *(const bvec8*)&As[(wm + mt * 16 + col) * BK + quad * 8];
#pragma unroll
        for (int nt = 0; nt < 4; nt++) bfv[nt] = *(const bvec8*)&Bs[(wn + nt * 16 + col) * BK + quad * 8];
#pragma unroll
        for (int mt = 0; mt < 4; mt++)
#pragma unroll
            for (int nt = 0; nt < 4; nt++)
                acc[mt][nt] = __builtin_amdgcn_mfma_f32_16x16x32_bf16(af[mt], bfv[nt], acc[mt][nt], 0, 0, 0);
    }

    // epilogue: C/D layout row = quad*4+r, col = lane&15
#pragma unroll
    for (int mt = 0; mt < 4; mt++) {
#pragma unroll
        for (int r = 0; r < 4; r++) {
            const int m = m0 + wm + mt * 16 + quad * 4 + r;
#pragma unroll
            for (int nt = 0; nt < 4; nt++) {
                const int n = n0 + wn + nt * 16 + col;
                float v = acc[mt][nt][r] + bias[n];
                if (OUT_BF16) ((u16*)Cv)[(size_t)m * N + n] = f32_to_bf16(v);
                else          ((float*)Cv)[(size_t)m * N + n] = v;
            }
        }
    }
}

// ---------------------------------------------------------------------------
// Flash attention: one block = (b, h, 64-row Q tile); 4 waves x 16 Q rows.
// QKV layout: qkv[(b*2048+t)*3072 + a*1024 + h*64 + d], a in {0=Q,1=K,2=V} (bf16)
// Y layout:   y[(b*2048+t)*1024 + h*64 + d]  (bf16)
// ---------------------------------------------------------------------------
__global__ __launch_bounds__(256) void attn_kernel(const u16* __restrict__ qkv,
                                                   u16* __restrict__ Y)
{
    __shared__ __attribute__((aligned(16))) u16 Qs [64 * 72];
    __shared__ __attribute__((aligned(16))) u16 Ks [64 * 72];
    __shared__ __attribute__((aligned(16))) u16 Vts[64 * 72];   // transposed: [d][s]
    __shared__ __attribute__((aligned(16))) u16 Ps [4 * 16 * 72];

    const int tid  = threadIdx.x;
    const int wave = tid >> 6;
    const int lane = tid & 63;
    const int col  = lane & 15;
    const int quad = lane >> 4;

    const int qt = blockIdx.x;
    const int h  = blockIdx.y;
    const int b  = blockIdx.z;
    const int q0 = qt * 64;

    const u16* qb = qkv + (size_t)b * 2048 * 3072;

    // stage Q tile (64 rows x 64 cols)
    {
        const int s = tid >> 2;
        const int c = (tid & 3) * 16;
        const u16* src = qb + (size_t)(q0 + s) * 3072 + h * 64 + c;
        *(uint4*)&Qs[s * 72 + c]     = *(const uint4*)src;
        *(uint4*)&Qs[s * 72 + c + 8] = *(const uint4*)(src + 8);
    }
    __syncthreads();

    bvec8 qf[2];
    qf[0] = *(const bvec8*)&Qs[(wave * 16 + col) * 72 + quad * 8];
    qf[1] = *(const bvec8*)&Qs[(wave * 16 + col) * 72 + 32 + quad * 8];

    float m_r[4], l_r[4];
    f32x4 o[4];
#pragma unroll
    for (int r = 0; r < 4; r++) { m_r[r] = -1e30f; l_r[r] = 0.f; }
#pragma unroll
    for (int d = 0; d < 4; d++) o[d] = f32x4{0.f, 0.f, 0.f, 0.f};

    for (int kt = 0; kt <= qt; ++kt) {
        const int s0 = kt * 64;
        __syncthreads();
        {   // stage K tile
            const int s = tid >> 2;
            const int c = (tid & 3) * 16;
            const u16* src = qb + (size_t)(s0 + s) * 3072 + 1024 + h * 64 + c;
            *(uint4*)&Ks[s * 72 + c]     = *(const uint4*)src;
            *(uint4*)&Ks[s * 72 + c + 8] = *(const uint4*)(src + 8);
        }
        {   // stage V tile transposed: Vts[d][s]
            const int s  = tid & 63;
            const int dg = (tid >> 6) * 16;
            const u16* src = qb + (size_t)(s0 + s) * 3072 + 2048 + h * 64 + dg;
            u16 tmp[16];
            *(uint4*)&tmp[0] = *(const uint4*)src;
            *(uint4*)&tmp[8] = *(const uint4*)(src + 8);
#pragma unroll
            for (int i = 0; i < 16; i++) Vts[(dg + i) * 72 + s] = tmp[i];
        }
        __syncthreads();

        // S = Q K^T  (16x64 per wave)
        f32x4 sv[4];
#pragma unroll
        for (int nt = 0; nt < 4; nt++) {
            sv[nt] = f32x4{0.f, 0.f, 0.f, 0.f};
            bvec8 kf0 = *(const bvec8*)&Ks[(nt * 16 + col) * 72 + quad * 8];
            bvec8 kf1 = *(const bvec8*)&Ks[(nt * 16 + col) * 72 + 32 + quad * 8];
            sv[nt] = __builtin_amdgcn_mfma_f32_16x16x32_bf16(qf[0], kf0, sv[nt], 0, 0, 0);
            sv[nt] = __builtin_amdgcn_mfma_f32_16x16x32_bf16(qf[1], kf1, sv[nt], 0, 0, 0);
        }

        const bool diag = (kt == qt);
        u16* pw = &Ps[wave * 16 * 72];
#pragma unroll
        for (int r = 0; r < 4; r++) {
            const int trow = wave * 16 + quad * 4 + r;
            float mx = -1e30f;
#pragma unroll
            for (int nt = 0; nt < 4; nt++) {
                float v = sv[nt][r] * 0.125f;            // 1/sqrt(64)
                if (diag && (nt * 16 + col) > trow) v = -3.0e38f;
                sv[nt][r] = v;
                mx = fmaxf(mx, v);
            }
            mx = fmaxf(mx, __shfl_xor(mx, 1));
            mx = fmaxf(mx, __shfl_xor(mx, 2));
            mx = fmaxf(mx, __shfl_xor(mx, 4));
            mx = fmaxf(mx, __shfl_xor(mx, 8));
            const float mo = m_r[r];
            const float mn = fmaxf(mo, mx);
            m_r[r] = mn;
            const float alpha = __expf(mo - mn);
            float rs = 0.f;
#pragma unroll
            for (int nt = 0; nt < 4; nt++) {
                float p = __expf(sv[nt][r] - mn);
                sv[nt][r] = p;
                rs += p;
            }
            rs += __shfl_xor(rs, 1);
            rs += __shfl_xor(rs, 2);
            rs += __shfl_xor(rs, 4);
            rs += __shfl_xor(rs, 8);
            l_r[r] = l_r[r] * alpha + rs;
#pragma unroll
            for (int d = 0; d < 4; d++) o[d][r] *= alpha;
#pragma unroll
            for (int nt = 0; nt < 4; nt++)
                pw[(quad * 4 + r) * 72 + nt * 16 + col] = f32_to_bf16(sv[nt][r]);
        }

        // O += P V : A-frag from Ps (m=col), B-frag from Vts (n=d, k=s)
#pragma unroll
        for (int ks = 0; ks < 2; ks++) {
            bvec8 pf = *(const bvec8*)&Ps[wave * 16 * 72 + col * 72 + ks * 32 + quad * 8];
#pragma unroll
            for (int d = 0; d < 4; d++) {
                bvec8 vf = *(const bvec8*)&Vts[(d * 16 + col) * 72 + ks * 32 + quad * 8];
                o[d] = __builtin_amdgcn_mfma_f32_16x16x32_bf16(pf, vf, o[d], 0, 0, 0);
            }
        }
    }

    // normalize + store Y (bf16)
#pragma unroll
    for (int r = 0; r < 4; r++) {
        const float inv = 1.0f / l_r[r];
        const int t = q0 + wave * 16 + quad * 4 + r;
#pragma unroll
        for (int d = 0; d < 4; d++) {
            Y[((size_t)(b * 2048 + t)) * 1024 + h * 64 + d * 16 + col] =
                f32_to_bf16(o[d][r] * inv);
        }
    }
}

// ---------------------------------------------------------------------------
extern "C" void kernel_launch(void* const* d_in, const int* in_sizes, int n_in,
                              void* d_out, int out_size, void* d_ws, size_t ws_size,
                              hipStream_t stream) {
    const float* x      = (const float*)d_in[0];   // [2,2048,1024] fp32
    const float* w_attn = (const float*)d_in[1];   // [3072,1024]   fp32
    const float* b_attn = (const float*)d_in[2];   // [3072]        fp32
    const float* w_proj = (const float*)d_in[3];   // [1024,1024]   fp32
    const float* b_proj = (const float*)d_in[4];   // [1024]        fp32
    float* out = (float*)d_out;                    // [2,2048,1024] fp32

    // workspace layout (bf16 u16 elements)
    u16* xb  = (u16*)d_ws;                          //  8 MB  4096x1024
    u16* wab = xb  + (size_t)4096 * 1024;           //  6 MB  3072x1024
    u16* wpb = wab + (size_t)3072 * 1024;           //  2 MB  1024x1024
    u16* qkv = wpb + (size_t)1024 * 1024;           // 24 MB  4096x3072
    u16* y   = qkv + (size_t)4096 * 3072;           //  8 MB  4096x1024

    // 0) convert fp32 inputs to bf16
    {
        int n4 = 4096 * 1024 / 4;
        cvt_f32_bf16<<<(n4 + 255) / 256, 256, 0, stream>>>(x, xb, n4);
        n4 = 3072 * 1024 / 4;
        cvt_f32_bf16<<<(n4 + 255) / 256, 256, 0, stream>>>(w_attn, wab, n4);
        n4 = 1024 * 1024 / 4;
        cvt_f32_bf16<<<(n4 + 255) / 256, 256, 0, stream>>>(w_proj, wpb, n4);
    }

    // 1) QKV = x @ w_attn^T + b_attn   (bf16 out)
    dim3 g1(3072 / BN, 4096 / BM);
    gemm_bt_bias<true><<<g1, 256, 0, stream>>>(xb, wab, b_attn, qkv, 4096, 3072, 1024);

    // 2) flash attention -> y (bf16)
    dim3 g2(2048 / 64, 16, 2);
    attn_kernel<<<g2, 256, 0, stream>>>(qkv, y);

    // 3) out = y @ w_proj^T + b_proj   (fp32 out)
    dim3 g3(1024 / BN, 4096 / BM);
    gemm_bt_bias<false><<<g3, 256, 0, stream>>>(y, wpb, b_proj, out, 4096, 1024, 1024);
}

// Round 3
// 212.208 us; speedup vs baseline: 1.3024x; 1.3024x over previous
//
#include <hip/hip_runtime.h>
#include <stdint.h>

typedef unsigned short u16;
typedef __attribute__((ext_vector_type(8))) __bf16 bvec8;
typedef __attribute__((ext_vector_type(4))) float f32x4;

__device__ __forceinline__ u16 f32_to_bf16(float f) {
    uint32_t u = __float_as_uint(f);
    u += 0x7fffu + ((u >> 16) & 1u);   // RNE
    return (u16)(u >> 16);
}

// async global->LDS, 16B/lane; LDS dest = wave-uniform base + lane*16 (HW rule)
__device__ __forceinline__ void gl2lds16(const u16* g, u16* l) {
    void* gnc = const_cast<void*>((const void*)g);
    __builtin_amdgcn_global_load_lds(
        (__attribute__((address_space(1))) uint32_t*)gnc,
        (__attribute__((address_space(3))) uint32_t*)((void*)l),
        16, 0, 0);
}

// ---------------------------------------------------------------------------
// fp32 -> bf16 for all three inputs in one launch
// ---------------------------------------------------------------------------
__global__ __launch_bounds__(256) void cvt3(
    const float* __restrict__ a, int na4, const float* __restrict__ b, int nb4,
    const float* __restrict__ c, int nc4,
    u16* __restrict__ oa, u16* __restrict__ ob, u16* __restrict__ oc)
{
    int i = blockIdx.x * 256 + threadIdx.x;
    const float* src; u16* dst; int off;
    if (i < na4)             { src = a; dst = oa; off = i; }
    else if (i < na4 + nb4)  { src = b; dst = ob; off = i - na4; }
    else if (i < na4 + nb4 + nc4) { src = c; dst = oc; off = i - na4 - nb4; }
    else return;
    float4 v = ((const float4*)src)[off];
    ushort4 o;
    o.x = f32_to_bf16(v.x); o.y = f32_to_bf16(v.y);
    o.z = f32_to_bf16(v.z); o.w = f32_to_bf16(v.w);
    ((ushort4*)dst)[off] = o;
}

// ---------------------------------------------------------------------------
// GEMM (B^T): C[M][N] = A[M][K]*B[N][K]^T + bias[N]; bf16 in, fp32 acc.
// BM=128, BK=32, BNt template (128 or 64). 256 thr = 4 waves as 2x2.
// ---------------------------------------------------------------------------
template <int BNt, bool OUT_BF16>
__global__ __launch_bounds__(256) void gemm_bt_bias(
    const u16* __restrict__ A, const u16* __restrict__ B,
    const float* __restrict__ bias, void* __restrict__ Cv,
    int M, int N, int K)
{
    constexpr int NT = BNt / 32;                 // n-frags per wave
    __shared__ __attribute__((aligned(16))) u16 As[128 * 32];
    __shared__ __attribute__((aligned(16))) u16 Bs[BNt * 32];

    const int tid = threadIdx.x, wave = tid >> 6, lane = tid & 63;
    const int col = lane & 15, quad = lane >> 4;
    const int m0 = blockIdx.y * 128, n0 = blockIdx.x * BNt;
    const int wm = (wave >> 1) * 64, wn = (wave & 1) * (BNt / 2);
    const int srow = lane >> 2, schunk = lane & 3;
    const u16* Ag = A + (size_t)(m0 + wave * 32) * K;

    f32x4 acc[4][NT];
#pragma unroll
    for (int i = 0; i < 4; i++)
#pragma unroll
        for (int j = 0; j < NT; j++) acc[i][j] = f32x4{0.f, 0.f, 0.f, 0.f};

    for (int k0 = 0; k0 < K; k0 += 32) {
        __syncthreads();
        gl2lds16(Ag + (size_t)(srow)      * K + k0 + schunk * 8, &As[(wave * 2 + 0) * 512]);
        gl2lds16(Ag + (size_t)(16 + srow) * K + k0 + schunk * 8, &As[(wave * 2 + 1) * 512]);
        if constexpr (BNt == 128) {
            const u16* Bg = B + (size_t)(n0 + wave * 32) * K;
            gl2lds16(Bg + (size_t)(srow)      * K + k0 + schunk * 8, &Bs[(wave * 2 + 0) * 512]);
            gl2lds16(Bg + (size_t)(16 + srow) * K + k0 + schunk * 8, &Bs[(wave * 2 + 1) * 512]);
        } else {
            const u16* Bg = B + (size_t)(n0 + wave * 16) * K;
            gl2lds16(Bg + (size_t)(srow)      * K + k0 + schunk * 8, &Bs[wave * 512]);
        }
        __syncthreads();

        bvec8 af[4], bfv[NT];
#pragma unroll
        for (int mt = 0; mt < 4; mt++)  af[mt]  = *(const bvec8*)&As[(wm + mt * 16 + col) * 32 + quad * 8];
#pragma unroll
        for (int nt = 0; nt < NT; nt++) bfv[nt] = *(const bvec8*)&Bs[(wn + nt * 16 + col) * 32 + quad * 8];
#pragma unroll
        for (int mt = 0; mt < 4; mt++)
#pragma unroll
            for (int nt = 0; nt < NT; nt++)
                acc[mt][nt] = __builtin_amdgcn_mfma_f32_16x16x32_bf16(af[mt], bfv[nt], acc[mt][nt], 0, 0, 0);
    }

#pragma unroll
    for (int mt = 0; mt < 4; mt++) {
#pragma unroll
        for (int r = 0; r < 4; r++) {
            const int m = m0 + wm + mt * 16 + quad * 4 + r;
#pragma unroll
            for (int nt = 0; nt < NT; nt++) {
                const int n = n0 + wn + nt * 16 + col;
                float v = acc[mt][nt][r] + bias[n];
                if (OUT_BF16) ((u16*)Cv)[(size_t)m * N + n] = f32_to_bf16(v);
                else          ((float*)Cv)[(size_t)m * N + n] = v;
            }
        }
    }
}

// ---------------------------------------------------------------------------
// V transpose: qkv V-region [b][t][h*64+d] -> vT[b][h][d][t]  (bf16)
// ---------------------------------------------------------------------------
__global__ __launch_bounds__(256) void transpose_v(const u16* __restrict__ qkv,
                                                   u16* __restrict__ vT)
{
    __shared__ u16 Ts[64 * 74];
    const int tid = threadIdx.x;
    const int t0 = blockIdx.x * 64, h = blockIdx.y, b = blockIdx.z;
    const u16* src = qkv + (size_t)b * 2048 * 3072 + 2048 + h * 64;
#pragma unroll
    for (int k2 = 0; k2 < 2; k2++) {
        int c = k2 * 256 + tid, tl = c >> 3, ch = c & 7;
        *(uint4*)&Ts[tl * 74 + ch * 8] = *(const uint4*)(src + (size_t)(t0 + tl) * 3072 + ch * 8);
    }
    __syncthreads();
    u16* dst = vT + (size_t)((b * 16 + h) * 64) * 2048;
#pragma unroll
    for (int k2 = 0; k2 < 2; k2++) {
        int c = k2 * 256 + tid, d = c >> 3, tch = c & 7;
        u16 tmp[8];
#pragma unroll
        for (int j2 = 0; j2 < 8; j2++) tmp[j2] = Ts[(tch * 8 + j2) * 74 + d];
        *(uint4*)&dst[(size_t)d * 2048 + t0 + tch * 8] = *(const uint4*)tmp;
    }
}

// ---------------------------------------------------------------------------
// Flash attention, no-max softmax (safe: sigma(S)~0.41, max ~2.5 << fp32 range).
// Tiles staged via gl2lds with XOR chunk swizzle (chunk ^= row&7) for bank spread.
// Block = (qt,h,b), 64 Q-rows, 4 waves x 16 rows. qt interleaved for balance.
// ---------------------------------------------------------------------------
__global__ __launch_bounds__(256) void attn_kernel(const u16* __restrict__ qkv,
                                                   const u16* __restrict__ vT,
                                                   u16* __restrict__ Y)
{
    __shared__ __attribute__((aligned(16))) u16 Qs[64 * 64];
    __shared__ __attribute__((aligned(16))) u16 Ks[64 * 64];
    __shared__ __attribute__((aligned(16))) u16 Vs[64 * 64];
    __shared__ __attribute__((aligned(16))) u16 Ps[4 * 16 * 72];

    const int tid = threadIdx.x, wave = tid >> 6, lane = tid & 63;
    const int col = lane & 15, quad = lane >> 4;

    const int j = blockIdx.x;
    const int qt = (j & 1) ? (j >> 1) : (31 - (j >> 1));   // interleave long/short
    const int h = blockIdx.y, b = blockIdx.z;
    const int q0 = qt * 64;

    const u16* qb = qkv + (size_t)b * 2048 * 3072;
    const u16* vb = vT + (size_t)((b * 16 + h) * 64) * 2048;

    // per-lane swizzled source params for the 2 staging calls
    const int c0 = wave * 64 + lane, c1 = 256 + c0;
    const int r0 = c0 >> 3, p0 = c0 & 7, r1 = c1 >> 3, p1 = c1 & 7;
    const int sw0 = (p0 ^ (r0 & 7)) * 8, sw1 = (p1 ^ (r1 & 7)) * 8;

    // stage Q (swizzled)
    gl2lds16(qb + (size_t)(q0 + r0) * 3072 + h * 64 + sw0, &Qs[wave * 512]);
    gl2lds16(qb + (size_t)(q0 + r1) * 3072 + h * 64 + sw1, &Qs[2048 + wave * 512]);
    __syncthreads();

    const int qrow = wave * 16 + col;
    bvec8 qf0 = *(const bvec8*)&Qs[qrow * 64 + ((quad       ^ (qrow & 7)) * 8)];
    bvec8 qf1 = *(const bvec8*)&Qs[qrow * 64 + (((4 + quad) ^ (qrow & 7)) * 8)];

    float l_acc[4] = {0.f, 0.f, 0.f, 0.f};
    f32x4 o[4];
#pragma unroll
    for (int d = 0; d < 4; d++) o[d] = f32x4{0.f, 0.f, 0.f, 0.f};

    const int tloc = wave * 16 + quad * 4;   // + r = local Q row in tile

    for (int kt = 0; kt <= qt; ++kt) {
        const int s0 = kt * 64;
        __syncthreads();   // previous iteration's readers done
        gl2lds16(qb + (size_t)(s0 + r0) * 3072 + 1024 + h * 64 + sw0, &Ks[wave * 512]);
        gl2lds16(qb + (size_t)(s0 + r1) * 3072 + 1024 + h * 64 + sw1, &Ks[2048 + wave * 512]);
        gl2lds16(vb + (size_t)r0 * 2048 + s0 + sw0, &Vs[wave * 512]);
        gl2lds16(vb + (size_t)r1 * 2048 + s0 + sw1, &Vs[2048 + wave * 512]);
        __syncthreads();   // vmcnt drain -> tiles visible

        // S = Q K^T (16x64 per wave)
        f32x4 sv[4];
#pragma unroll
        for (int nt = 0; nt < 4; nt++) {
            const int krow = nt * 16 + col;
            bvec8 kf0 = *(const bvec8*)&Ks[krow * 64 + ((quad       ^ (krow & 7)) * 8)];
            bvec8 kf1 = *(const bvec8*)&Ks[krow * 64 + (((4 + quad) ^ (krow & 7)) * 8)];
            sv[nt] = f32x4{0.f, 0.f, 0.f, 0.f};
            sv[nt] = __builtin_amdgcn_mfma_f32_16x16x32_bf16(qf0, kf0, sv[nt], 0, 0, 0);
            sv[nt] = __builtin_amdgcn_mfma_f32_16x16x32_bf16(qf1, kf1, sv[nt], 0, 0, 0);
        }

        // no-max softmax: p = exp(S/8); mask diag; accumulate l in-lane
        const bool diag = (kt == qt);
        u16* pw = &Ps[wave * 16 * 72];
#pragma unroll
        for (int nt = 0; nt < 4; nt++) {
#pragma unroll
            for (int r = 0; r < 4; r++) {
                float p = __expf(sv[nt][r] * 0.125f);
                if (diag && (nt * 16 + col) > (tloc + r)) p = 0.f;
                l_acc[r] += p;
                pw[(quad * 4 + r) * 72 + nt * 16 + col] = f32_to_bf16(p);
            }
        }

        // O += P V : A-frag from own Ps region, B-frag from swizzled Vs
#pragma unroll
        for (int ks = 0; ks < 2; ks++) {
            bvec8 pf = *(const bvec8*)&Ps[wave * 16 * 72 + col * 72 + ks * 32 + quad * 8];
#pragma unroll
            for (int d = 0; d < 4; d++) {
                const int vrow = d * 16 + col;
                bvec8 vf = *(const bvec8*)&Vs[vrow * 64 + (((ks * 4 + quad) ^ (vrow & 7)) * 8)];
                o[d] = __builtin_amdgcn_mfma_f32_16x16x32_bf16(pf, vf, o[d], 0, 0, 0);
            }
        }
    }

    // reduce l across the 16-col lane group (once per task)
#pragma unroll
    for (int r = 0; r < 4; r++) {
        float s = l_acc[r];
        s += __shfl_xor(s, 1); s += __shfl_xor(s, 2);
        s += __shfl_xor(s, 4); s += __shfl_xor(s, 8);
        l_acc[r] = s;
    }

#pragma unroll
    for (int r = 0; r < 4; r++) {
        const float inv = 1.0f / l_acc[r];
        const int t = q0 + wave * 16 + quad * 4 + r;
#pragma unroll
        for (int d = 0; d < 4; d++)
            Y[(size_t)(b * 2048 + t) * 1024 + h * 64 + d * 16 + col] =
                f32_to_bf16(o[d][r] * inv);
    }
}

// ---------------------------------------------------------------------------
extern "C" void kernel_launch(void* const* d_in, const int* in_sizes, int n_in,
                              void* d_out, int out_size, void* d_ws, size_t ws_size,
                              hipStream_t stream) {
    const float* x      = (const float*)d_in[0];
    const float* w_attn = (const float*)d_in[1];
    const float* b_attn = (const float*)d_in[2];
    const float* w_proj = (const float*)d_in[3];
    const float* b_proj = (const float*)d_in[4];
    float* out = (float*)d_out;

    // ws (u16 elements): xb 4096x1024 | wab 3072x1024 | wpb 1024x1024 |
    //                    qkv 4096x3072 | y 4096x1024 ; vT overlays xb (dead after GEMM1)
    u16* xb  = (u16*)d_ws;
    u16* wab = xb  + (size_t)4096 * 1024;
    u16* wpb = wab + (size_t)3072 * 1024;
    u16* qkv = wpb + (size_t)1024 * 1024;
    u16* y   = qkv + (size_t)4096 * 3072;
    u16* vT  = xb;                               // reuse: 2*16*64*2048 = 4096*1024

    const int na4 = 4096 * 1024 / 4, nb4 = 3072 * 1024 / 4, nc4 = 1024 * 1024 / 4;
    cvt3<<<(na4 + nb4 + nc4 + 255) / 256, 256, 0, stream>>>(
        x, na4, w_attn, nb4, w_proj, nc4, xb, wab, wpb);

    dim3 g1(3072 / 128, 4096 / 128);
    gemm_bt_bias<128, true><<<g1, 256, 0, stream>>>(xb, wab, b_attn, qkv, 4096, 3072, 1024);

    dim3 gt(32, 16, 2);
    transpose_v<<<gt, 256, 0, stream>>>(qkv, vT);

    dim3 g2(32, 16, 2);
    attn_kernel<<<g2, 256, 0, stream>>>(qkv, vT, y);

    dim3 g3(1024 / 64, 4096 / 128);
    gemm_bt_bias<64, false><<<g3, 256, 0, stream>>>(y, wpb, b_proj, out, 4096, 1024, 1024);
}

// Round 4
// 198.239 us; speedup vs baseline: 1.3941x; 1.0705x over previous
//
#include <hip/hip_runtime.h>
#include <stdint.h>

typedef unsigned short u16;
typedef __attribute__((ext_vector_type(8))) __bf16 bvec8;
typedef __attribute__((ext_vector_type(4))) float f32x4;

__device__ __forceinline__ u16 f32_to_bf16(float f) {
    uint32_t u = __float_as_uint(f);
    u += 0x7fffu + ((u >> 16) & 1u);   // RNE
    return (u16)(u >> 16);
}

// async global->LDS, 16B/lane; LDS dest = wave-uniform base + lane*16 (HW rule)
__device__ __forceinline__ void gl2lds16(const u16* g, u16* l) {
    void* gnc = const_cast<void*>((const void*)g);
    __builtin_amdgcn_global_load_lds(
        (__attribute__((address_space(1))) uint32_t*)gnc,
        (__attribute__((address_space(3))) uint32_t*)((void*)l),
        16, 0, 0);
}

// ---------------------------------------------------------------------------
// fp32 -> bf16 for all three inputs in one launch
// ---------------------------------------------------------------------------
__global__ __launch_bounds__(256) void cvt3(
    const float* __restrict__ a, int na4, const float* __restrict__ b, int nb4,
    const float* __restrict__ c, int nc4,
    u16* __restrict__ oa, u16* __restrict__ ob, u16* __restrict__ oc)
{
    int i = blockIdx.x * 256 + threadIdx.x;
    const float* src; u16* dst; int off;
    if (i < na4)             { src = a; dst = oa; off = i; }
    else if (i < na4 + nb4)  { src = b; dst = ob; off = i - na4; }
    else if (i < na4 + nb4 + nc4) { src = c; dst = oc; off = i - na4 - nb4; }
    else return;
    float4 v = ((const float4*)src)[off];
    ushort4 o;
    o.x = f32_to_bf16(v.x); o.y = f32_to_bf16(v.y);
    o.z = f32_to_bf16(v.z); o.w = f32_to_bf16(v.w);
    ((ushort4*)dst)[off] = o;
}

// ---------------------------------------------------------------------------
// GEMM (B^T): C[M][N] = A[M][K]*B[N][K]^T + bias[N]; bf16 in, fp32 acc.
// BM=128, BK=32, BNt template (128 or 64). 256 thr = 4 waves as 2x2.
// ---------------------------------------------------------------------------
template <int BNt, bool OUT_BF16>
__global__ __launch_bounds__(256) void gemm_bt_bias(
    const u16* __restrict__ A, const u16* __restrict__ B,
    const float* __restrict__ bias, void* __restrict__ Cv,
    int M, int N, int K)
{
    constexpr int NT = BNt / 32;                 // n-frags per wave
    __shared__ __attribute__((aligned(16))) u16 As[128 * 32];
    __shared__ __attribute__((aligned(16))) u16 Bs[BNt * 32];

    const int tid = threadIdx.x, wave = tid >> 6, lane = tid & 63;
    const int col = lane & 15, quad = lane >> 4;
    const int m0 = blockIdx.y * 128, n0 = blockIdx.x * BNt;
    const int wm = (wave >> 1) * 64, wn = (wave & 1) * (BNt / 2);
    const int srow = lane >> 2, schunk = lane & 3;
    const u16* Ag = A + (size_t)(m0 + wave * 32) * K;

    f32x4 acc[4][NT];
#pragma unroll
    for (int i = 0; i < 4; i++)
#pragma unroll
        for (int j = 0; j < NT; j++) acc[i][j] = f32x4{0.f, 0.f, 0.f, 0.f};

    for (int k0 = 0; k0 < K; k0 += 32) {
        __syncthreads();
        gl2lds16(Ag + (size_t)(srow)      * K + k0 + schunk * 8, &As[(wave * 2 + 0) * 512]);
        gl2lds16(Ag + (size_t)(16 + srow) * K + k0 + schunk * 8, &As[(wave * 2 + 1) * 512]);
        if constexpr (BNt == 128) {
            const u16* Bg = B + (size_t)(n0 + wave * 32) * K;
            gl2lds16(Bg + (size_t)(srow)      * K + k0 + schunk * 8, &Bs[(wave * 2 + 0) * 512]);
            gl2lds16(Bg + (size_t)(16 + srow) * K + k0 + schunk * 8, &Bs[(wave * 2 + 1) * 512]);
        } else {
            const u16* Bg = B + (size_t)(n0 + wave * 16) * K;
            gl2lds16(Bg + (size_t)(srow)      * K + k0 + schunk * 8, &Bs[wave * 512]);
        }
        __syncthreads();

        bvec8 af[4], bfv[NT];
#pragma unroll
        for (int mt = 0; mt < 4; mt++)  af[mt]  = *(const bvec8*)&As[(wm + mt * 16 + col) * 32 + quad * 8];
#pragma unroll
        for (int nt = 0; nt < NT; nt++) bfv[nt] = *(const bvec8*)&Bs[(wn + nt * 16 + col) * 32 + quad * 8];
#pragma unroll
        for (int mt = 0; mt < 4; mt++)
#pragma unroll
            for (int nt = 0; nt < NT; nt++)
                acc[mt][nt] = __builtin_amdgcn_mfma_f32_16x16x32_bf16(af[mt], bfv[nt], acc[mt][nt], 0, 0, 0);
    }

#pragma unroll
    for (int mt = 0; mt < 4; mt++) {
#pragma unroll
        for (int r = 0; r < 4; r++) {
            const int m = m0 + wm + mt * 16 + quad * 4 + r;
#pragma unroll
            for (int nt = 0; nt < NT; nt++) {
                const int n = n0 + wn + nt * 16 + col;
                float v = acc[mt][nt][r] + bias[n];
                if (OUT_BF16) ((u16*)Cv)[(size_t)m * N + n] = f32_to_bf16(v);
                else          ((float*)Cv)[(size_t)m * N + n] = v;
            }
        }
    }
}

// ---------------------------------------------------------------------------
// V transpose: qkv V-region [b][t][h*64+d] -> vT[b][h][d][t]  (bf16)
// ---------------------------------------------------------------------------
__global__ __launch_bounds__(256) void transpose_v(const u16* __restrict__ qkv,
                                                   u16* __restrict__ vT)
{
    __shared__ u16 Ts[64 * 74];
    const int tid = threadIdx.x;
    const int t0 = blockIdx.x * 64, h = blockIdx.y, b = blockIdx.z;
    const u16* src = qkv + (size_t)b * 2048 * 3072 + 2048 + h * 64;
#pragma unroll
    for (int k2 = 0; k2 < 2; k2++) {
        int c = k2 * 256 + tid, tl = c >> 3, ch = c & 7;
        *(uint4*)&Ts[tl * 74 + ch * 8] = *(const uint4*)(src + (size_t)(t0 + tl) * 3072 + ch * 8);
    }
    __syncthreads();
    u16* dst = vT + (size_t)((b * 16 + h) * 64) * 2048;
#pragma unroll
    for (int k2 = 0; k2 < 2; k2++) {
        int c = k2 * 256 + tid, d = c >> 3, tch = c & 7;
        u16 tmp[8];
#pragma unroll
        for (int j2 = 0; j2 < 8; j2++) tmp[j2] = Ts[(tch * 8 + j2) * 74 + d];
        *(uint4*)&dst[(size_t)d * 2048 + t0 + tch * 8] = *(const uint4*)tmp;
    }
}

// ---------------------------------------------------------------------------
// Flash attention, no-max softmax. Each block serially processes the
// COMPLEMENTARY Q-tile pair (s, 31-s): (s+1)+(32-s) = 33 tile-iters for every
// block -> perfect load balance regardless of dispatch/placement policy.
// 512 blocks = 2/CU. Tiles staged via gl2lds with XOR chunk swizzle.
// ---------------------------------------------------------------------------
__global__ __launch_bounds__(256) void attn_kernel(const u16* __restrict__ qkv,
                                                   const u16* __restrict__ vT,
                                                   u16* __restrict__ Y)
{
    __shared__ __attribute__((aligned(16))) u16 Qs[64 * 64];
    __shared__ __attribute__((aligned(16))) u16 Ks[64 * 64];
    __shared__ __attribute__((aligned(16))) u16 Vs[64 * 64];
    __shared__ __attribute__((aligned(16))) u16 Ps[4 * 16 * 72];

    const int tid = threadIdx.x, wave = tid >> 6, lane = tid & 63;
    const int col = lane & 15, quad = lane >> 4;

    const int s_idx = blockIdx.x;            // 0..15 -> pair (s_idx, 31-s_idx)
    const int h = blockIdx.y, b = blockIdx.z;

    const u16* qb = qkv + (size_t)b * 2048 * 3072;
    const u16* vb = vT + (size_t)((b * 16 + h) * 64) * 2048;

    // per-lane swizzled source params for the 2 staging calls per tile
    const int c0 = wave * 64 + lane, c1 = 256 + c0;
    const int r0 = c0 >> 3, p0 = c0 & 7, r1 = c1 >> 3, p1 = c1 & 7;
    const int sw0 = (p0 ^ (r0 & 7)) * 8, sw1 = (p1 ^ (r1 & 7)) * 8;

    const int tloc = wave * 16 + quad * 4;   // + r = local Q row in tile

#pragma unroll
    for (int phase = 0; phase < 2; ++phase) {
        const int qt = phase ? (31 - s_idx) : s_idx;
        const int q0 = qt * 64;

        __syncthreads();   // previous phase's readers of Qs/Ks/Vs/Ps done
        gl2lds16(qb + (size_t)(q0 + r0) * 3072 + h * 64 + sw0, &Qs[wave * 512]);
        gl2lds16(qb + (size_t)(q0 + r1) * 3072 + h * 64 + sw1, &Qs[2048 + wave * 512]);
        __syncthreads();

        const int qrow = wave * 16 + col;
        bvec8 qf0 = *(const bvec8*)&Qs[qrow * 64 + ((quad       ^ (qrow & 7)) * 8)];
        bvec8 qf1 = *(const bvec8*)&Qs[qrow * 64 + (((4 + quad) ^ (qrow & 7)) * 8)];

        float l_acc[4] = {0.f, 0.f, 0.f, 0.f};
        f32x4 o[4];
#pragma unroll
        for (int d = 0; d < 4; d++) o[d] = f32x4{0.f, 0.f, 0.f, 0.f};

        for (int kt = 0; kt <= qt; ++kt) {
            const int s0 = kt * 64;
            __syncthreads();   // previous iteration's readers done
            gl2lds16(qb + (size_t)(s0 + r0) * 3072 + 1024 + h * 64 + sw0, &Ks[wave * 512]);
            gl2lds16(qb + (size_t)(s0 + r1) * 3072 + 1024 + h * 64 + sw1, &Ks[2048 + wave * 512]);
            gl2lds16(vb + (size_t)r0 * 2048 + s0 + sw0, &Vs[wave * 512]);
            gl2lds16(vb + (size_t)r1 * 2048 + s0 + sw1, &Vs[2048 + wave * 512]);
            __syncthreads();   // vmcnt drain -> tiles visible

            // S = Q K^T (16x64 per wave)
            f32x4 sv[4];
#pragma unroll
            for (int nt = 0; nt < 4; nt++) {
                const int krow = nt * 16 + col;
                bvec8 kf0 = *(const bvec8*)&Ks[krow * 64 + ((quad       ^ (krow & 7)) * 8)];
                bvec8 kf1 = *(const bvec8*)&Ks[krow * 64 + (((4 + quad) ^ (krow & 7)) * 8)];
                sv[nt] = f32x4{0.f, 0.f, 0.f, 0.f};
                sv[nt] = __builtin_amdgcn_mfma_f32_16x16x32_bf16(qf0, kf0, sv[nt], 0, 0, 0);
                sv[nt] = __builtin_amdgcn_mfma_f32_16x16x32_bf16(qf1, kf1, sv[nt], 0, 0, 0);
            }

            // no-max softmax: p = exp(S/8); mask diag; accumulate l in-lane
            const bool diag = (kt == qt);
            u16* pw = &Ps[wave * 16 * 72];
#pragma unroll
            for (int nt = 0; nt < 4; nt++) {
#pragma unroll
                for (int r = 0; r < 4; r++) {
                    float p = __expf(sv[nt][r] * 0.125f);
                    if (diag && (nt * 16 + col) > (tloc + r)) p = 0.f;
                    l_acc[r] += p;
                    pw[(quad * 4 + r) * 72 + nt * 16 + col] = f32_to_bf16(p);
                }
            }

            // O += P V
#pragma unroll
            for (int ks = 0; ks < 2; ks++) {
                bvec8 pf = *(const bvec8*)&Ps[wave * 16 * 72 + col * 72 + ks * 32 + quad * 8];
#pragma unroll
                for (int d = 0; d < 4; d++) {
                    const int vrow = d * 16 + col;
                    bvec8 vf = *(const bvec8*)&Vs[vrow * 64 + (((ks * 4 + quad) ^ (vrow & 7)) * 8)];
                    o[d] = __builtin_amdgcn_mfma_f32_16x16x32_bf16(pf, vf, o[d], 0, 0, 0);
                }
            }
        }

        // reduce l across the 16-col lane group; normalize; store
#pragma unroll
        for (int r = 0; r < 4; r++) {
            float s = l_acc[r];
            s += __shfl_xor(s, 1); s += __shfl_xor(s, 2);
            s += __shfl_xor(s, 4); s += __shfl_xor(s, 8);
            const float inv = 1.0f / s;
            const int t = q0 + wave * 16 + quad * 4 + r;
#pragma unroll
            for (int d = 0; d < 4; d++)
                Y[(size_t)(b * 2048 + t) * 1024 + h * 64 + d * 16 + col] =
                    f32_to_bf16(o[d][r] * inv);
        }
    }
}

// ---------------------------------------------------------------------------
extern "C" void kernel_launch(void* const* d_in, const int* in_sizes, int n_in,
                              void* d_out, int out_size, void* d_ws, size_t ws_size,
                              hipStream_t stream) {
    const float* x      = (const float*)d_in[0];
    const float* w_attn = (const float*)d_in[1];
    const float* b_attn = (const float*)d_in[2];
    const float* w_proj = (const float*)d_in[3];
    const float* b_proj = (const float*)d_in[4];
    float* out = (float*)d_out;

    // ws (u16 elements): xb 4096x1024 | wab 3072x1024 | wpb 1024x1024 |
    //                    qkv 4096x3072 | y 4096x1024 ; vT overlays xb (dead after GEMM1)
    u16* xb  = (u16*)d_ws;
    u16* wab = xb  + (size_t)4096 * 1024;
    u16* wpb = wab + (size_t)3072 * 1024;
    u16* qkv = wpb + (size_t)1024 * 1024;
    u16* y   = qkv + (size_t)4096 * 3072;
    u16* vT  = xb;                               // reuse: 2*16*64*2048 = 4096*1024

    const int na4 = 4096 * 1024 / 4, nb4 = 3072 * 1024 / 4, nc4 = 1024 * 1024 / 4;
    cvt3<<<(na4 + nb4 + nc4 + 255) / 256, 256, 0, stream>>>(
        x, na4, w_attn, nb4, w_proj, nc4, xb, wab, wpb);

    dim3 g1(3072 / 128, 4096 / 128);
    gemm_bt_bias<128, true><<<g1, 256, 0, stream>>>(xb, wab, b_attn, qkv, 4096, 3072, 1024);

    dim3 gt(32, 16, 2);
    transpose_v<<<gt, 256, 0, stream>>>(qkv, vT);

    dim3 g2(16, 16, 2);   // complementary-pair blocks: perfect balance
    attn_kernel<<<g2, 256, 0, stream>>>(qkv, vT, y);

    dim3 g3(1024 / 64, 4096 / 128);
    gemm_bt_bias<64, false><<<g3, 256, 0, stream>>>(y, wpb, b_proj, out, 4096, 1024, 1024);
}

// Round 5
// 193.084 us; speedup vs baseline: 1.4314x; 1.0267x over previous
//
#include <hip/hip_runtime.h>
#include <stdint.h>

typedef unsigned short u16;
typedef __attribute__((ext_vector_type(8))) __bf16 bvec8;
typedef __attribute__((ext_vector_type(4))) float f32x4;

__device__ __forceinline__ u16 f32_to_bf16(float f) {
    uint32_t u = __float_as_uint(f);
    u += 0x7fffu + ((u >> 16) & 1u);   // RNE
    return (u16)(u >> 16);
}

// async global->LDS, 16B/lane; LDS dest = wave-uniform base + lane*16 (HW rule)
__device__ __forceinline__ void gl2lds16(const u16* g, u16* l) {
    void* gnc = const_cast<void*>((const void*)g);
    __builtin_amdgcn_global_load_lds(
        (__attribute__((address_space(1))) uint32_t*)gnc,
        (__attribute__((address_space(3))) uint32_t*)((void*)l),
        16, 0, 0);
}

// ---------------------------------------------------------------------------
// fp32 -> bf16 for all three inputs in one launch
// ---------------------------------------------------------------------------
__global__ __launch_bounds__(256) void cvt3(
    const float* __restrict__ a, int na4, const float* __restrict__ b, int nb4,
    const float* __restrict__ c, int nc4,
    u16* __restrict__ oa, u16* __restrict__ ob, u16* __restrict__ oc)
{
    int i = blockIdx.x * 256 + threadIdx.x;
    const float* src; u16* dst; int off;
    if (i < na4)             { src = a; dst = oa; off = i; }
    else if (i < na4 + nb4)  { src = b; dst = ob; off = i - na4; }
    else if (i < na4 + nb4 + nc4) { src = c; dst = oc; off = i - na4 - nb4; }
    else return;
    float4 v = ((const float4*)src)[off];
    ushort4 o;
    o.x = f32_to_bf16(v.x); o.y = f32_to_bf16(v.y);
    o.z = f32_to_bf16(v.z); o.w = f32_to_bf16(v.w);
    ((ushort4*)dst)[off] = o;
}

// ---------------------------------------------------------------------------
// GEMM (B^T): C[M][N] = A[M][K]*B[N][K]^T + bias[N]; bf16 in, fp32 acc.
// BM=128, BK=32, BNt template (128 or 64). 256 thr = 4 waves as 2x2.
// ---------------------------------------------------------------------------
template <int BNt, bool OUT_BF16>
__global__ __launch_bounds__(256) void gemm_bt_bias(
    const u16* __restrict__ A, const u16* __restrict__ B,
    const float* __restrict__ bias, void* __restrict__ Cv,
    int M, int N, int K)
{
    constexpr int NT = BNt / 32;                 // n-frags per wave
    __shared__ __attribute__((aligned(16))) u16 As[128 * 32];
    __shared__ __attribute__((aligned(16))) u16 Bs[BNt * 32];

    const int tid = threadIdx.x, wave = tid >> 6, lane = tid & 63;
    const int col = lane & 15, quad = lane >> 4;
    const int m0 = blockIdx.y * 128, n0 = blockIdx.x * BNt;
    const int wm = (wave >> 1) * 64, wn = (wave & 1) * (BNt / 2);
    const int srow = lane >> 2, schunk = lane & 3;
    const u16* Ag = A + (size_t)(m0 + wave * 32) * K;

    f32x4 acc[4][NT];
#pragma unroll
    for (int i = 0; i < 4; i++)
#pragma unroll
        for (int j = 0; j < NT; j++) acc[i][j] = f32x4{0.f, 0.f, 0.f, 0.f};

    for (int k0 = 0; k0 < K; k0 += 32) {
        __syncthreads();
        gl2lds16(Ag + (size_t)(srow)      * K + k0 + schunk * 8, &As[(wave * 2 + 0) * 512]);
        gl2lds16(Ag + (size_t)(16 + srow) * K + k0 + schunk * 8, &As[(wave * 2 + 1) * 512]);
        if constexpr (BNt == 128) {
            const u16* Bg = B + (size_t)(n0 + wave * 32) * K;
            gl2lds16(Bg + (size_t)(srow)      * K + k0 + schunk * 8, &Bs[(wave * 2 + 0) * 512]);
            gl2lds16(Bg + (size_t)(16 + srow) * K + k0 + schunk * 8, &Bs[(wave * 2 + 1) * 512]);
        } else {
            const u16* Bg = B + (size_t)(n0 + wave * 16) * K;
            gl2lds16(Bg + (size_t)(srow)      * K + k0 + schunk * 8, &Bs[wave * 512]);
        }
        __syncthreads();

        bvec8 af[4], bfv[NT];
#pragma unroll
        for (int mt = 0; mt < 4; mt++)  af[mt]  = *(const bvec8*)&As[(wm + mt * 16 + col) * 32 + quad * 8];
#pragma unroll
        for (int nt = 0; nt < NT; nt++) bfv[nt] = *(const bvec8*)&Bs[(wn + nt * 16 + col) * 32 + quad * 8];
#pragma unroll
        for (int mt = 0; mt < 4; mt++)
#pragma unroll
            for (int nt = 0; nt < NT; nt++)
                acc[mt][nt] = __builtin_amdgcn_mfma_f32_16x16x32_bf16(af[mt], bfv[nt], acc[mt][nt], 0, 0, 0);
    }

#pragma unroll
    for (int mt = 0; mt < 4; mt++) {
#pragma unroll
        for (int r = 0; r < 4; r++) {
            const int m = m0 + wm + mt * 16 + quad * 4 + r;
#pragma unroll
            for (int nt = 0; nt < NT; nt++) {
                const int n = n0 + wn + nt * 16 + col;
                float v = acc[mt][nt][r] + bias[n];
                if (OUT_BF16) ((u16*)Cv)[(size_t)m * N + n] = f32_to_bf16(v);
                else          ((float*)Cv)[(size_t)m * N + n] = v;
            }
        }
    }
}

// ---------------------------------------------------------------------------
// V transpose: qkv V-region [b][t][h*64+d] -> vT[b][h][d][t]  (bf16)
// ---------------------------------------------------------------------------
__global__ __launch_bounds__(256) void transpose_v(const u16* __restrict__ qkv,
                                                   u16* __restrict__ vT)
{
    __shared__ u16 Ts[64 * 74];
    const int tid = threadIdx.x;
    const int t0 = blockIdx.x * 64, h = blockIdx.y, b = blockIdx.z;
    const u16* src = qkv + (size_t)b * 2048 * 3072 + 2048 + h * 64;
#pragma unroll
    for (int k2 = 0; k2 < 2; k2++) {
        int c = k2 * 256 + tid, tl = c >> 3, ch = c & 7;
        *(uint4*)&Ts[tl * 74 + ch * 8] = *(const uint4*)(src + (size_t)(t0 + tl) * 3072 + ch * 8);
    }
    __syncthreads();
    u16* dst = vT + (size_t)((b * 16 + h) * 64) * 2048;
#pragma unroll
    for (int k2 = 0; k2 < 2; k2++) {
        int c = k2 * 256 + tid, d = c >> 3, tch = c & 7;
        u16 tmp[8];
#pragma unroll
        for (int j2 = 0; j2 < 8; j2++) tmp[j2] = Ts[(tch * 8 + j2) * 74 + d];
        *(uint4*)&dst[(size_t)d * 2048 + t0 + tch * 8] = *(const uint4*)tmp;
    }
}

// ---------------------------------------------------------------------------
// Flash attention, no-max softmax. Complementary pair (s,31-s) per block.
// Grid (32,16,1): x = b*16+h  =>  all 16 blocks of a head share one XCD
// (linear%8 = x%8) so K/V live in that XCD's L2.
// K/V double-buffered via global_load_lds + raw s_barrier/s_waitcnt vmcnt(4):
// tile kt+1's DMA is in flight while tile kt computes (never drain to 0).
// ---------------------------------------------------------------------------
__global__ __launch_bounds__(256) void attn_kernel(const u16* __restrict__ qkv,
                                                   const u16* __restrict__ vT,
                                                   u16* __restrict__ Y)
{
    __shared__ __attribute__((aligned(16))) u16 Qs[64 * 64];
    __shared__ __attribute__((aligned(16))) u16 Ks[2][64 * 64];
    __shared__ __attribute__((aligned(16))) u16 Vs[2][64 * 64];
    __shared__ __attribute__((aligned(16))) u16 Ps[4 * 16 * 72];

    const int tid = threadIdx.x, wave = tid >> 6, lane = tid & 63;
    const int col = lane & 15, quad = lane >> 4;

    const int g = blockIdx.x;                // b*16 + h
    const int b = g >> 4, h = g & 15;
    const int s_idx = blockIdx.y;            // pair (s_idx, 31-s_idx)

    const u16* qb = qkv + (size_t)b * 2048 * 3072;
    const u16* vb = vT + (size_t)g * 64 * 2048;

    // per-lane swizzled source params for the 2 staging calls per tile
    const int c0 = wave * 64 + lane, c1 = 256 + c0;
    const int r0 = c0 >> 3, p0 = c0 & 7, r1 = c1 >> 3, p1 = c1 & 7;
    const int sw0 = (p0 ^ (r0 & 7)) * 8, sw1 = (p1 ^ (r1 & 7)) * 8;

    const int tloc = wave * 16 + quad * 4;   // + r = local Q row in tile

#pragma unroll
    for (int phase = 0; phase < 2; ++phase) {
        const int qt = phase ? (31 - s_idx) : s_idx;
        const int q0 = qt * 64;

        __syncthreads();   // phase-0 readers done; also drains Y stores
        gl2lds16(qb + (size_t)(q0 + r0) * 3072 + h * 64 + sw0, &Qs[wave * 512]);
        gl2lds16(qb + (size_t)(q0 + r1) * 3072 + h * 64 + sw1, &Qs[2048 + wave * 512]);
        __syncthreads();   // Q visible to all waves

        const int qrow = wave * 16 + col;
        bvec8 qf0 = *(const bvec8*)&Qs[qrow * 64 + ((quad       ^ (qrow & 7)) * 8)];
        bvec8 qf1 = *(const bvec8*)&Qs[qrow * 64 + (((4 + quad) ^ (qrow & 7)) * 8)];

        float l_acc[4] = {0.f, 0.f, 0.f, 0.f};
        f32x4 o[4];
#pragma unroll
        for (int d = 0; d < 4; d++) o[d] = f32x4{0.f, 0.f, 0.f, 0.f};

        // prologue: issue tile 0 into buffer 0
        {
            gl2lds16(qb + (size_t)(r0) * 3072 + 1024 + h * 64 + sw0, &Ks[0][wave * 512]);
            gl2lds16(qb + (size_t)(r1) * 3072 + 1024 + h * 64 + sw1, &Ks[0][2048 + wave * 512]);
            gl2lds16(vb + (size_t)r0 * 2048 + sw0, &Vs[0][wave * 512]);
            gl2lds16(vb + (size_t)r1 * 2048 + sw1, &Vs[0][2048 + wave * 512]);
        }

        for (int kt = 0; kt <= qt; ++kt) {
            const int cur = kt & 1;
            if (kt < qt) {
                const int s0n = (kt + 1) * 64;
                const int nb2 = cur ^ 1;
                gl2lds16(qb + (size_t)(s0n + r0) * 3072 + 1024 + h * 64 + sw0, &Ks[nb2][wave * 512]);
                gl2lds16(qb + (size_t)(s0n + r1) * 3072 + 1024 + h * 64 + sw1, &Ks[nb2][2048 + wave * 512]);
                gl2lds16(vb + (size_t)r0 * 2048 + s0n + sw0, &Vs[nb2][wave * 512]);
                gl2lds16(vb + (size_t)r1 * 2048 + s0n + sw1, &Vs[nb2][2048 + wave * 512]);
                asm volatile("s_waitcnt vmcnt(4)" ::: "memory");   // cur tile landed; next in flight
            } else {
                asm volatile("s_waitcnt vmcnt(0)" ::: "memory");   // last tile landed
            }
            asm volatile("s_barrier" ::: "memory");                 // all waves see cur tile

            // S = Q K^T (16x64 per wave)
            f32x4 sv[4];
#pragma unroll
            for (int nt = 0; nt < 4; nt++) {
                const int krow = nt * 16 + col;
                bvec8 kf0 = *(const bvec8*)&Ks[cur][krow * 64 + ((quad       ^ (krow & 7)) * 8)];
                bvec8 kf1 = *(const bvec8*)&Ks[cur][krow * 64 + (((4 + quad) ^ (krow & 7)) * 8)];
                sv[nt] = f32x4{0.f, 0.f, 0.f, 0.f};
                sv[nt] = __builtin_amdgcn_mfma_f32_16x16x32_bf16(qf0, kf0, sv[nt], 0, 0, 0);
                sv[nt] = __builtin_amdgcn_mfma_f32_16x16x32_bf16(qf1, kf1, sv[nt], 0, 0, 0);
            }

            // no-max softmax: p = exp(S/8); mask diag; accumulate l in-lane
            const bool diag = (kt == qt);
            u16* pw = &Ps[wave * 16 * 72];
#pragma unroll
            for (int nt = 0; nt < 4; nt++) {
#pragma unroll
                for (int r = 0; r < 4; r++) {
                    float p = __expf(sv[nt][r] * 0.125f);
                    if (diag && (nt * 16 + col) > (tloc + r)) p = 0.f;
                    l_acc[r] += p;
                    pw[(quad * 4 + r) * 72 + nt * 16 + col] = f32_to_bf16(p);
                }
            }

            // O += P V   (Ps strictly same-wave; compiler handles lgkmcnt)
#pragma unroll
            for (int ks = 0; ks < 2; ks++) {
                bvec8 pf = *(const bvec8*)&Ps[wave * 16 * 72 + col * 72 + ks * 32 + quad * 8];
#pragma unroll
                for (int d = 0; d < 4; d++) {
                    const int vrow = d * 16 + col;
                    bvec8 vf = *(const bvec8*)&Vs[cur][vrow * 64 + (((ks * 4 + quad) ^ (vrow & 7)) * 8)];
                    o[d] = __builtin_amdgcn_mfma_f32_16x16x32_bf16(pf, vf, o[d], 0, 0, 0);
                }
            }
            asm volatile("s_barrier" ::: "memory");   // readers done before buf reuse
        }

        // reduce l across the 16-col lane group; normalize; store
#pragma unroll
        for (int r = 0; r < 4; r++) {
            float s = l_acc[r];
            s += __shfl_xor(s, 1); s += __shfl_xor(s, 2);
            s += __shfl_xor(s, 4); s += __shfl_xor(s, 8);
            const float inv = 1.0f / s;
            const int t = q0 + wave * 16 + quad * 4 + r;
#pragma unroll
            for (int d = 0; d < 4; d++)
                Y[(size_t)(b * 2048 + t) * 1024 + h * 64 + d * 16 + col] =
                    f32_to_bf16(o[d][r] * inv);
        }
    }
}

// ---------------------------------------------------------------------------
extern "C" void kernel_launch(void* const* d_in, const int* in_sizes, int n_in,
                              void* d_out, int out_size, void* d_ws, size_t ws_size,
                              hipStream_t stream) {
    const float* x      = (const float*)d_in[0];
    const float* w_attn = (const float*)d_in[1];
    const float* b_attn = (const float*)d_in[2];
    const float* w_proj = (const float*)d_in[3];
    const float* b_proj = (const float*)d_in[4];
    float* out = (float*)d_out;

    // ws (u16 elements): xb 4096x1024 | wab 3072x1024 | wpb 1024x1024 |
    //                    qkv 4096x3072 | y 4096x1024 ; vT overlays xb (dead after GEMM1)
    u16* xb  = (u16*)d_ws;
    u16* wab = xb  + (size_t)4096 * 1024;
    u16* wpb = wab + (size_t)3072 * 1024;
    u16* qkv = wpb + (size_t)1024 * 1024;
    u16* y   = qkv + (size_t)4096 * 3072;
    u16* vT  = xb;                               // reuse: 2*16*64*2048 = 4096*1024

    const int na4 = 4096 * 1024 / 4, nb4 = 3072 * 1024 / 4, nc4 = 1024 * 1024 / 4;
    cvt3<<<(na4 + nb4 + nc4 + 255) / 256, 256, 0, stream>>>(
        x, na4, w_attn, nb4, w_proj, nc4, xb, wab, wpb);

    dim3 g1(3072 / 128, 4096 / 128);
    gemm_bt_bias<128, true><<<g1, 256, 0, stream>>>(xb, wab, b_attn, qkv, 4096, 3072, 1024);

    dim3 gt(32, 16, 2);
    transpose_v<<<gt, 256, 0, stream>>>(qkv, vT);

    dim3 g2(32, 16, 1);   // x = b*16+h (XCD-local K/V), y = pair index
    attn_kernel<<<g2, 256, 0, stream>>>(qkv, vT, y);

    dim3 g3(1024 / 64, 4096 / 128);
    gemm_bt_bias<64, false><<<g3, 256, 0, stream>>>(y, wpb, b_proj, out, 4096, 1024, 1024);
}